// Round 3
// baseline (126.142 us; speedup 1.0000x reference)
//
#include <hip/hip_runtime.h>
#include <hip/hip_bf16.h>

#define LSEQ 2048
#define BB 2
#define DD 128
#define HH 8
#define HD 32

#define FPSCALE 524288.0f            // 2^19 fixed-point scale for S
#define RFPSCALE (1.0f / 524288.0f)
#define QSCALE 0.25503486f           // (1/sqrt(32)) * log2(e)  -> use exp2

typedef __bf16 bf8_t __attribute__((ext_vector_type(8)));
typedef __bf16 bf4_t __attribute__((ext_vector_type(4)));
typedef float f4_t __attribute__((ext_vector_type(4)));

// raw 2^x (scores are small & well-conditioned; no denormal/edge fixup needed)
static __device__ __forceinline__ float fexp2(float x) {
#if __has_builtin(__builtin_amdgcn_exp2f)
    return __builtin_amdgcn_exp2f(x);
#else
    float r;
    asm("v_exp_f32 %0, %1" : "=v"(r) : "v"(x));
    return r;
#endif
}

// ---------------- kernel A: QK-GEMM + wv sigmoid + zero Si/cnt ----------
// blocks 0..511   : Q/K = (x+pe) @ W (+bias); 64 rows x 64 cols per block
// blocks 512..639 : w[hb][k] = sigmoid(x[b,L-1-k] . Wv[:,h]) * FPSCALE
// blocks 640..671 : zero Si (int4)
// block 672       : zero cnt[16]
__global__ __launch_bounds__(256) void k_A(const float* __restrict__ x,
                                           const float* __restrict__ pe,
                                           const float* __restrict__ Wq,
                                           const float* __restrict__ Wk,
                                           const float* __restrict__ Wv,
                                           const float* __restrict__ bq,
                                           const float* __restrict__ bk,
                                           float* __restrict__ w,
                                           __bf16* __restrict__ Qb,
                                           __bf16* __restrict__ Kb,
                                           int* __restrict__ Si,
                                           int* __restrict__ cnt) {
    __shared__ __align__(16) char smem[34816];
    int gb = blockIdx.x;
    int tid = threadIdx.x;

    if (gb < 512) {
        // ---- QK GEMM role: 64 rows x 64 cols ----
        __bf16* xs = (__bf16*)smem;                   // 64 x 136
        __bf16* Wt = (__bf16*)(smem + 64 * 136 * 2);  // 64 x 136 (c-major, transposed)
        int jr = gb >> 3, y = gb & 7;
        int row0 = jr * 64;
        bool isK = y >= 4;
        int cbase = (y & 3) * 64;
        const float* W = isK ? Wk : Wq;

        // stage x+pe -> bf16 LDS (64 rows x 128 cols), float4 loads
        #pragma unroll
        for (int i = 0; i < 8; i++) {
            int idx4 = tid + i * 256;                 // 0..2047 float4s
            int row = idx4 >> 5, col4 = idx4 & 31;
            float4 xv = ((const float4*)x)[row0 * 32 + idx4];
            float4 pv = ((const float4*)pe)[((row0 + row) & (LSEQ - 1)) * 32 + col4];
            bf4_t o = {(__bf16)(xv.x + pv.x), (__bf16)(xv.y + pv.y),
                       (__bf16)(xv.z + pv.z), (__bf16)(xv.w + pv.w)};
            *(bf4_t*)&xs[row * 136 + col4 * 4] = o;
        }
        // stage W stripe transposed: Wt[c][d] = W[d][cbase+c]
        #pragma unroll
        for (int i = 0; i < 8; i++) {
            int idx4 = tid + i * 256;                 // 0..2047
            int d = idx4 >> 4, c4 = (idx4 & 15) * 4;
            float4 wv4 = *(const float4*)(W + d * 256 + cbase + c4);
            Wt[(c4 + 0) * 136 + d] = (__bf16)wv4.x;
            Wt[(c4 + 1) * 136 + d] = (__bf16)wv4.y;
            Wt[(c4 + 2) * 136 + d] = (__bf16)wv4.z;
            Wt[(c4 + 3) * 136 + d] = (__bf16)wv4.w;
        }
        __syncthreads();

        int wid = tid >> 6, lane = tid & 63;
        int lm = lane & 15, lq = lane >> 4;
        int c0loc = wid * 16;
        f4_t acc0 = {0,0,0,0}, acc1 = {0,0,0,0}, acc2 = {0,0,0,0}, acc3 = {0,0,0,0};
        #pragma unroll
        for (int s = 0; s < 4; s++) {
            bf8_t bw = *(const bf8_t*)&Wt[(c0loc + lm) * 136 + lq * 8 + s * 32];
            bf8_t a0 = *(const bf8_t*)&xs[(0  + lm) * 136 + lq * 8 + s * 32];
            bf8_t a1 = *(const bf8_t*)&xs[(16 + lm) * 136 + lq * 8 + s * 32];
            bf8_t a2 = *(const bf8_t*)&xs[(32 + lm) * 136 + lq * 8 + s * 32];
            bf8_t a3 = *(const bf8_t*)&xs[(48 + lm) * 136 + lq * 8 + s * 32];
            acc0 = __builtin_amdgcn_mfma_f32_16x16x32_bf16(a0, bw, acc0, 0, 0, 0);
            acc1 = __builtin_amdgcn_mfma_f32_16x16x32_bf16(a1, bw, acc1, 0, 0, 0);
            acc2 = __builtin_amdgcn_mfma_f32_16x16x32_bf16(a2, bw, acc2, 0, 0, 0);
            acc3 = __builtin_amdgcn_mfma_f32_16x16x32_bf16(a3, bw, acc3, 0, 0, 0);
        }
        int c = cbase + c0loc + lm;                   // 0..255
        float bv = (isK ? bk : bq)[c];
        float qs = isK ? 1.f : QSCALE;
        __bf16* Out = isK ? Kb : Qb;
        int h = c >> 5, hd = c & 31;
        f4_t accs[4] = {acc0, acc1, acc2, acc3};
        #pragma unroll
        for (int rs = 0; rs < 4; rs++) {
            #pragma unroll
            for (int r = 0; r < 4; r++) {
                int row = row0 + rs * 16 + lq * 4 + r;   // = b*2048 + l
                int b_ = row >> 11, l = row & (LSEQ - 1);
                Out[((h * BB + b_) * LSEQ + l) * HD + hd] =
                    (__bf16)((accs[rs][r] + bv) * qs);
            }
        }
    } else if (gb < 640) {
        // ---- wv sigmoid role (FPSCALE folded in) ----
        float* xsf = (float*)smem;                    // 32*132
        float* wvf = (float*)(smem + 32 * 132 * 4);   // 1024
        int r0 = (gb - 512) * 32;
        for (int i = 0; i < 16; i++) {
            int idx = tid + i * 256;
            xsf[(idx >> 7) * 132 + (idx & 127)] = x[r0 * 128 + idx];
        }
        for (int i = 0; i < 4; i++) {
            int idx = tid + i * 256;
            wvf[idx] = Wv[idx];
        }
        __syncthreads();
        int rl = tid >> 3, h = tid & 7;
        float acc = 0.f;
        #pragma unroll 8
        for (int d = 0; d < 128; d++) acc += xsf[rl * 132 + d] * wvf[d * 8 + h];
        float sg = 1.f / (1.f + __expf(-acc));
        int r = r0 + rl;
        int b = r >> 11, l = r & (LSEQ - 1);
        w[(h * BB + b) * LSEQ + (LSEQ - 1 - l)] = sg * FPSCALE;
    } else if (gb < 672) {
        int4 z = {0, 0, 0, 0};
        ((int4*)Si)[(gb - 640) * 256 + tid] = z;
    } else {
        if (tid < 16) cnt[tid] = 0;
    }
}

// ---------------- kernel F: fused den + scatter + last-block pooling --------
// grid (128 q-stripes, 16 hb), 256 threads = 4 waves, each block owns 16 q rows.
// phase 1: den[q] = sum_k exp2(s) over ALL k (waves split k 4-way, LDS reduce)
// phase 2: scatter exp2(s)*rdv*w into block-shared 2048-bin LDS, k >= q0 only
// phase 3: device-scope atomic accumulate into S
// phase 4: __syncthreads (drains vmcnt for the whole block) -> counter bump;
//          the block that arrives LAST (old==127) pools S -> out.  NO fences.
__global__ __launch_bounds__(256) void k_F(const __bf16* __restrict__ Qb,
                                           const __bf16* __restrict__ Kb,
                                           const float* __restrict__ w,
                                           int* __restrict__ S,
                                           int* __restrict__ cnt,
                                           float* __restrict__ out) {
    __shared__ int Sloc[2048];
    __shared__ float dred[64];
    __shared__ float rdv_s[16];
    __shared__ int lastFlag;

    int hb = blockIdx.y;
    int q0 = blockIdx.x << 4;
    int tid = threadIdx.x;
    int wid = tid >> 6, lane = tid & 63;
    int lm = lane & 15, lq = lane >> 4;

    int4 z4 = {0, 0, 0, 0};
    ((int4*)Sloc)[tid] = z4;
    ((int4*)Sloc)[tid + 256] = z4;

    const __bf16* Qhb = Qb + hb * LSEQ * HD;
    const __bf16* Khb = Kb + hb * LSEQ * HD;
    bf8_t aq = *(const bf8_t*)(Qhb + (q0 + lm) * HD + lq * 8);

    // ---- phase 1: denominators over all k ----
    float dsum[4] = {0.f, 0.f, 0.f, 0.f};
    #pragma unroll 4
    for (int s = wid; s < 128; s += 4) {
        bf8_t bk_ = *(const bf8_t*)(Khb + (s * 16 + lm) * HD + lq * 8);
        f4_t z = {0.f, 0.f, 0.f, 0.f};
        f4_t sc = __builtin_amdgcn_mfma_f32_16x16x32_bf16(aq, bk_, z, 0, 0, 0);
        #pragma unroll
        for (int r = 0; r < 4; r++) dsum[r] += fexp2(sc[r]);
    }
    #pragma unroll
    for (int r = 0; r < 4; r++) {
        float v = dsum[r];
        v += __shfl_xor(v, 1);
        v += __shfl_xor(v, 2);
        v += __shfl_xor(v, 4);
        v += __shfl_xor(v, 8);
        dsum[r] = v;
    }
    if (lm == 0) {
        #pragma unroll
        for (int r = 0; r < 4; r++) dred[wid * 16 + lq * 4 + r] = dsum[r];
    }
    __syncthreads();
    if (tid < 16) {
        float d = dred[tid] + dred[16 + tid] + dred[32 + tid] + dred[48 + tid];
        rdv_s[tid] = 1.0f / d;
    }
    __syncthreads();
    float rdv[4];
    #pragma unroll
    for (int r = 0; r < 4; r++) rdv[r] = rdv_s[lq * 4 + r];

    // ---- phase 2: upper-triangle scatter ----
    int nsub = 128 - (q0 >> 4);                  // subtiles j, k0s = q0 + 16*j
    const float* whb = w + hb * LSEQ;
    int qrow = q0 + lq * 4;
    int qc = (nsub + 3) >> 2;                    // contiguous chunk per wave
    int jlo = wid * qc;
    int jhi = jlo + qc; if (jhi > nsub) jhi = nsub;

    if (wid == 0) {
        // boundary subtile j=0: per-element m>=0 mask
        bf8_t bk_ = *(const bf8_t*)(Khb + (q0 + lm) * HD + lq * 8);
        f4_t z = {0.f, 0.f, 0.f, 0.f};
        f4_t sc = __builtin_amdgcn_mfma_f32_16x16x32_bf16(aq, bk_, z, 0, 0, 0);
        float wv = whb[q0 + lm];
        #pragma unroll
        for (int r = 0; r < 4; r++) {
            int m = lm - lq * 4 - r;
            if (m >= 0) {
                int iv = __float2int_rn(fexp2(sc[r]) * rdv[r] * wv);
                atomicAdd(&Sloc[m], iv);
            }
        }
        jlo = 1;
    }
    #pragma unroll 2
    for (int j = jlo; j < jhi; j++) {
        int k0s = q0 + j * 16;
        bf8_t bk_ = *(const bf8_t*)(Khb + (k0s + lm) * HD + lq * 8);
        f4_t z = {0.f, 0.f, 0.f, 0.f};
        f4_t sc = __builtin_amdgcn_mfma_f32_16x16x32_bf16(aq, bk_, z, 0, 0, 0);
        float wv = whb[k0s + lm];
        int base = k0s + lm - qrow;              // m for r=0; strictly > 0 here
        #pragma unroll
        for (int r = 0; r < 4; r++) {
            int iv = __float2int_rn(fexp2(sc[r]) * rdv[r] * wv);
            atomicAdd(&Sloc[base - r], iv);      // native ds_add
        }
    }
    __syncthreads();

    // ---- phase 3: global atomic accumulate (device-scope, no fence) ----
    int M = LSEQ - q0;
    int* Sg = S + hb * LSEQ;
    for (int i = tid; i < M; i += 256) {
        int v = Sloc[i];
        if (v) atomicAdd(&Sg[i], v);
    }

    // ---- phase 4: last-arriving block per hb does the pooling epilogue ----
    // __syncthreads drains each wave's vmcnt before the barrier, so every
    // atomicAdd above has completed at the coherence point when tid 0 bumps
    // the counter. The block seeing old==127 is the LAST one -> S is final.
    __syncthreads();
    if (tid == 0) lastFlag = (atomicAdd(&cnt[hb], 1) == 127);
    __syncthreads();
    if (!lastFlag) return;

    for (int m = tid; m < LSEQ; m += 256)
        Sloc[m] = __hip_atomic_load(&Sg[m], __ATOMIC_RELAXED,
                                    __HIP_MEMORY_SCOPE_AGENT);
    __syncthreads();
    int h = hb >> 1, b = hb & 1;
    for (int m = tid; m < LSEQ; m += 256) {
        float s = (float)Sloc[m];
        float c = 3.f;
        if (m > 0) s += (float)Sloc[m - 1]; else c = 2.f;
        if (m < LSEQ - 1) s += (float)Sloc[m + 1]; else c = 2.f;
        out[(b * LSEQ + m) * 8 + h] = s * RFPSCALE / c;
    }
}

extern "C" void kernel_launch(void* const* d_in, const int* in_sizes, int n_in,
                              void* d_out, int out_size, void* d_ws, size_t ws_size,
                              hipStream_t stream) {
    const float* x  = (const float*)d_in[0];
    const float* pe = (const float*)d_in[1];
    const float* Wq = (const float*)d_in[2];
    const float* bq = (const float*)d_in[3];
    const float* Wk = (const float*)d_in[4];
    const float* bk = (const float*)d_in[5];
    const float* Wv = (const float*)d_in[6];
    float* out = (float*)d_out;

    char* ws = (char*)d_ws;
    int*    Si  = (int*)(ws);                              // 128 KB
    float*  w   = (float*)(ws + 131072);                   // 128 KB
    __bf16* Qb  = (__bf16*)(ws + 262144);                  // 2 MB
    __bf16* Kb  = (__bf16*)(ws + 262144 + 2097152);        // 2 MB
    int*    cnt = (int*)(ws + 262144 + 4194304);           // 64 B

    k_A<<<673, 256, 0, stream>>>(x, pe, Wq, Wk, Wv, bq, bk, w, Qb, Kb, Si, cnt);
    k_F<<<dim3(128, 16), 256, 0, stream>>>(Qb, Kb, w, Si, cnt, out);
}

// Round 4
// 119.663 us; speedup vs baseline: 1.0541x; 1.0541x over previous
//
#include <hip/hip_runtime.h>
#include <hip/hip_bf16.h>

#define LSEQ 2048
#define BB 2
#define DD 128
#define HH 8
#define HD 32

#define FPSCALE 524288.0f            // 2^19 fixed-point scale for S
#define RFPSCALE (1.0f / 524288.0f)
#define QSCALE 0.25503486f           // (1/sqrt(32)) * log2(e)  -> use exp2

#define RSTRIDE 2060                 // per-lq Sloc region stride (ints);
                                     // (RSTRIDE-4)%32==8 -> lq bank offsets {0,8,16,24}
                                     // => max 2 lanes/bank, zero same-address RMW

typedef __bf16 bf8_t __attribute__((ext_vector_type(8)));
typedef __bf16 bf4_t __attribute__((ext_vector_type(4)));
typedef float f4_t __attribute__((ext_vector_type(4)));

// raw 2^x (scores are small & well-conditioned; no denormal/edge fixup needed)
static __device__ __forceinline__ float fexp2(float x) {
#if __has_builtin(__builtin_amdgcn_exp2f)
    return __builtin_amdgcn_exp2f(x);
#else
    float r;
    asm("v_exp_f32 %0, %1" : "=v"(r) : "v"(x));
    return r;
#endif
}

// ---------------- kernel A: QK-GEMM + wv sigmoid + zero Si ----------
// blocks 0..511   : Q/K = (x+pe) @ W (+bias); 64 rows x 64 cols per block
// blocks 512..639 : w[hb][k] = sigmoid(x[b,L-1-k] . Wv[:,h]) * FPSCALE
// blocks 640..671 : zero Si (int4)
__global__ __launch_bounds__(256) void k_A(const float* __restrict__ x,
                                           const float* __restrict__ pe,
                                           const float* __restrict__ Wq,
                                           const float* __restrict__ Wk,
                                           const float* __restrict__ Wv,
                                           const float* __restrict__ bq,
                                           const float* __restrict__ bk,
                                           float* __restrict__ w,
                                           __bf16* __restrict__ Qb,
                                           __bf16* __restrict__ Kb,
                                           int* __restrict__ Si) {
    __shared__ __align__(16) char smem[34816];
    int gb = blockIdx.x;
    int tid = threadIdx.x;

    if (gb < 512) {
        // ---- QK GEMM role: 64 rows x 64 cols ----
        __bf16* xs = (__bf16*)smem;                   // 64 x 136
        __bf16* Wt = (__bf16*)(smem + 64 * 136 * 2);  // 64 x 136 (c-major, transposed)
        int jr = gb >> 3, y = gb & 7;
        int row0 = jr * 64;
        bool isK = y >= 4;
        int cbase = (y & 3) * 64;
        const float* W = isK ? Wk : Wq;

        // stage x+pe -> bf16 LDS (64 rows x 128 cols), float4 loads
        #pragma unroll
        for (int i = 0; i < 8; i++) {
            int idx4 = tid + i * 256;                 // 0..2047 float4s
            int row = idx4 >> 5, col4 = idx4 & 31;
            float4 xv = ((const float4*)x)[row0 * 32 + idx4];
            float4 pv = ((const float4*)pe)[((row0 + row) & (LSEQ - 1)) * 32 + col4];
            bf4_t o = {(__bf16)(xv.x + pv.x), (__bf16)(xv.y + pv.y),
                       (__bf16)(xv.z + pv.z), (__bf16)(xv.w + pv.w)};
            *(bf4_t*)&xs[row * 136 + col4 * 4] = o;
        }
        // stage W stripe transposed: Wt[c][d] = W[d][cbase+c]
        #pragma unroll
        for (int i = 0; i < 8; i++) {
            int idx4 = tid + i * 256;                 // 0..2047
            int d = idx4 >> 4, c4 = (idx4 & 15) * 4;
            float4 wv4 = *(const float4*)(W + d * 256 + cbase + c4);
            Wt[(c4 + 0) * 136 + d] = (__bf16)wv4.x;
            Wt[(c4 + 1) * 136 + d] = (__bf16)wv4.y;
            Wt[(c4 + 2) * 136 + d] = (__bf16)wv4.z;
            Wt[(c4 + 3) * 136 + d] = (__bf16)wv4.w;
        }
        __syncthreads();

        int wid = tid >> 6, lane = tid & 63;
        int lm = lane & 15, lq = lane >> 4;
        int c0loc = wid * 16;
        f4_t acc0 = {0,0,0,0}, acc1 = {0,0,0,0}, acc2 = {0,0,0,0}, acc3 = {0,0,0,0};
        #pragma unroll
        for (int s = 0; s < 4; s++) {
            bf8_t bw = *(const bf8_t*)&Wt[(c0loc + lm) * 136 + lq * 8 + s * 32];
            bf8_t a0 = *(const bf8_t*)&xs[(0  + lm) * 136 + lq * 8 + s * 32];
            bf8_t a1 = *(const bf8_t*)&xs[(16 + lm) * 136 + lq * 8 + s * 32];
            bf8_t a2 = *(const bf8_t*)&xs[(32 + lm) * 136 + lq * 8 + s * 32];
            bf8_t a3 = *(const bf8_t*)&xs[(48 + lm) * 136 + lq * 8 + s * 32];
            acc0 = __builtin_amdgcn_mfma_f32_16x16x32_bf16(a0, bw, acc0, 0, 0, 0);
            acc1 = __builtin_amdgcn_mfma_f32_16x16x32_bf16(a1, bw, acc1, 0, 0, 0);
            acc2 = __builtin_amdgcn_mfma_f32_16x16x32_bf16(a2, bw, acc2, 0, 0, 0);
            acc3 = __builtin_amdgcn_mfma_f32_16x16x32_bf16(a3, bw, acc3, 0, 0, 0);
        }
        int c = cbase + c0loc + lm;                   // 0..255
        float bv = (isK ? bk : bq)[c];
        float qs = isK ? 1.f : QSCALE;
        __bf16* Out = isK ? Kb : Qb;
        int h = c >> 5, hd = c & 31;
        f4_t accs[4] = {acc0, acc1, acc2, acc3};
        #pragma unroll
        for (int rs = 0; rs < 4; rs++) {
            #pragma unroll
            for (int r = 0; r < 4; r++) {
                int row = row0 + rs * 16 + lq * 4 + r;   // = b*2048 + l
                int b_ = row >> 11, l = row & (LSEQ - 1);
                Out[((h * BB + b_) * LSEQ + l) * HD + hd] =
                    (__bf16)((accs[rs][r] + bv) * qs);
            }
        }
    } else if (gb < 640) {
        // ---- wv sigmoid role (FPSCALE folded in) ----
        float* xsf = (float*)smem;                    // 32*132
        float* wvf = (float*)(smem + 32 * 132 * 4);   // 1024
        int r0 = (gb - 512) * 32;
        for (int i = 0; i < 16; i++) {
            int idx = tid + i * 256;
            xsf[(idx >> 7) * 132 + (idx & 127)] = x[r0 * 128 + idx];
        }
        for (int i = 0; i < 4; i++) {
            int idx = tid + i * 256;
            wvf[idx] = Wv[idx];
        }
        __syncthreads();
        int rl = tid >> 3, h = tid & 7;
        float acc = 0.f;
        #pragma unroll 8
        for (int d = 0; d < 128; d++) acc += xsf[rl * 132 + d] * wvf[d * 8 + h];
        float sg = 1.f / (1.f + __expf(-acc));
        int r = r0 + rl;
        int b = r >> 11, l = r & (LSEQ - 1);
        w[(h * BB + b) * LSEQ + (LSEQ - 1 - l)] = sg * FPSCALE;
    } else {
        int4 z = {0, 0, 0, 0};
        ((int4*)Si)[(gb - 640) * 256 + tid] = z;
    }
}

// ---------------- kernel F: fused den + triangle scatter --------------------
// grid (128 q-stripes, 16 hb), 256 threads = 4 waves, each block owns 16 q rows.
// phase 1: den[q] = sum_k exp2(s) over ALL k (waves split k 4-way, LDS reduce)
// phase 2: scatter exp2(s)*rdv*w into 4 per-lq LDS bin regions (stride RSTRIDE)
//          -> all 64 lane addresses in a ds_add are DISTINCT (no same-address
//          RMW serialization), banks spread {0,8,16,24}+lm -> max 2-way (free)
// phase 3: merge the 4 regions, device-scope atomic accumulate into S
__global__ __launch_bounds__(256) void k_F(const __bf16* __restrict__ Qb,
                                           const __bf16* __restrict__ Kb,
                                           const float* __restrict__ w,
                                           int* __restrict__ S) {
    __shared__ int Sloc[4 * RSTRIDE];                // 32960 B
    __shared__ float dred[64];
    __shared__ float rdv_s[16];

    int hb = blockIdx.y;
    int q0 = blockIdx.x << 4;
    int tid = threadIdx.x;
    int wid = tid >> 6, lane = tid & 63;
    int lm = lane & 15, lq = lane >> 4;

    int4 z4 = {0, 0, 0, 0};
    #pragma unroll
    for (int i = 0; i < 9; i++) {
        int idx4 = tid + i * 256;
        if (idx4 < RSTRIDE) ((int4*)Sloc)[idx4] = z4;   // 2060 int4 = 4*RSTRIDE ints
    }

    const __bf16* Qhb = Qb + hb * LSEQ * HD;
    const __bf16* Khb = Kb + hb * LSEQ * HD;
    bf8_t aq = *(const bf8_t*)(Qhb + (q0 + lm) * HD + lq * 8);

    // ---- phase 1: denominators over all k ----
    float dsum[4] = {0.f, 0.f, 0.f, 0.f};
    #pragma unroll 4
    for (int s = wid; s < 128; s += 4) {
        bf8_t bk_ = *(const bf8_t*)(Khb + (s * 16 + lm) * HD + lq * 8);
        f4_t z = {0.f, 0.f, 0.f, 0.f};
        f4_t sc = __builtin_amdgcn_mfma_f32_16x16x32_bf16(aq, bk_, z, 0, 0, 0);
        #pragma unroll
        for (int r = 0; r < 4; r++) dsum[r] += fexp2(sc[r]);
    }
    #pragma unroll
    for (int r = 0; r < 4; r++) {
        float v = dsum[r];
        v += __shfl_xor(v, 1);
        v += __shfl_xor(v, 2);
        v += __shfl_xor(v, 4);
        v += __shfl_xor(v, 8);
        dsum[r] = v;
    }
    if (lm == 0) {
        #pragma unroll
        for (int r = 0; r < 4; r++) dred[wid * 16 + lq * 4 + r] = dsum[r];
    }
    __syncthreads();
    if (tid < 16) {
        float d = dred[tid] + dred[16 + tid] + dred[32 + tid] + dred[48 + tid];
        rdv_s[tid] = 1.0f / d;
    }
    __syncthreads();
    float rdv[4];
    #pragma unroll
    for (int r = 0; r < 4; r++) rdv[r] = rdv_s[lq * 4 + r];

    // ---- phase 2: upper-triangle scatter into per-lq regions ----
    int nsub = 128 - (q0 >> 4);                  // subtiles j, k0s = q0 + 16*j
    const float* whb = w + hb * LSEQ;
    int qrow = q0 + lq * 4;
    int* myS = Sloc + lq * RSTRIDE;              // per-lq region
    int qc = (nsub + 3) >> 2;                    // contiguous chunk per wave
    int jlo = wid * qc;
    int jhi = jlo + qc; if (jhi > nsub) jhi = nsub;

    if (wid == 0) {
        // boundary subtile j=0: per-element m>=0 mask
        bf8_t bk_ = *(const bf8_t*)(Khb + (q0 + lm) * HD + lq * 8);
        f4_t z = {0.f, 0.f, 0.f, 0.f};
        f4_t sc = __builtin_amdgcn_mfma_f32_16x16x32_bf16(aq, bk_, z, 0, 0, 0);
        float wv = whb[q0 + lm];
        #pragma unroll
        for (int r = 0; r < 4; r++) {
            int m = lm - lq * 4 - r;
            if (m >= 0) {
                int iv = __float2int_rn(fexp2(sc[r]) * rdv[r] * wv);
                atomicAdd(&myS[m], iv);
            }
        }
        jlo = 1;
    }
    #pragma unroll 2
    for (int j = jlo; j < jhi; j++) {
        int k0s = q0 + j * 16;
        bf8_t bk_ = *(const bf8_t*)(Khb + (k0s + lm) * HD + lq * 8);
        f4_t z = {0.f, 0.f, 0.f, 0.f};
        f4_t sc = __builtin_amdgcn_mfma_f32_16x16x32_bf16(aq, bk_, z, 0, 0, 0);
        float wv = whb[k0s + lm];
        int base = k0s + lm - qrow;              // m for r=0; strictly > 0 here
        #pragma unroll
        for (int r = 0; r < 4; r++) {
            int iv = __float2int_rn(fexp2(sc[r]) * rdv[r] * wv);
            atomicAdd(&myS[base - r], iv);       // distinct addrs across the wave
        }
    }
    __syncthreads();

    // ---- phase 3: merge regions + global atomic accumulate ----
    int M = LSEQ - q0;
    int* Sg = S + hb * LSEQ;
    for (int i = tid; i < M; i += 256) {
        int v = Sloc[i] + Sloc[RSTRIDE + i] + Sloc[2 * RSTRIDE + i] +
                Sloc[3 * RSTRIDE + i];
        if (v) atomicAdd(&Sg[i], v);
    }
}

// ---------------- kernel 3: pooling epilogue (int -> float) ----------------
__global__ __launch_bounds__(256) void k_out(const int* __restrict__ S,
                                             float* __restrict__ out) {
    int idx = blockIdx.x * 256 + threadIdx.x;       // (b*2048 + m)*8 + h
    int h = idx & 7;
    int m = (idx >> 3) & (LSEQ - 1);
    int b = idx >> 14;
    const int* Sr = S + (h * BB + b) * LSEQ;
    float s = (float)Sr[m];
    float cnt = 3.f;
    if (m > 0) s += (float)Sr[m - 1]; else cnt = 2.f;
    if (m < LSEQ - 1) s += (float)Sr[m + 1]; else cnt = 2.f;
    out[idx] = s * RFPSCALE / cnt;
}

extern "C" void kernel_launch(void* const* d_in, const int* in_sizes, int n_in,
                              void* d_out, int out_size, void* d_ws, size_t ws_size,
                              hipStream_t stream) {
    const float* x  = (const float*)d_in[0];
    const float* pe = (const float*)d_in[1];
    const float* Wq = (const float*)d_in[2];
    const float* bq = (const float*)d_in[3];
    const float* Wk = (const float*)d_in[4];
    const float* bk = (const float*)d_in[5];
    const float* Wv = (const float*)d_in[6];
    float* out = (float*)d_out;

    char* ws = (char*)d_ws;
    int*    Si  = (int*)(ws);                              // 128 KB
    float*  w   = (float*)(ws + 131072);                   // 128 KB
    __bf16* Qb  = (__bf16*)(ws + 262144);                  // 2 MB
    __bf16* Kb  = (__bf16*)(ws + 262144 + 2097152);        // 2 MB

    k_A<<<672, 256, 0, stream>>>(x, pe, Wq, Wk, Wv, bq, bk, w, Qb, Kb, Si);
    k_F<<<dim3(128, 16), 256, 0, stream>>>(Qb, Kb, w, Si);
    k_out<<<128, 256, 0, stream>>>(Si, out);
}

// Round 7
// 113.018 us; speedup vs baseline: 1.1161x; 1.0588x over previous
//
#include <hip/hip_runtime.h>
#include <hip/hip_bf16.h>

#define LSEQ 2048
#define BB 2
#define DD 128
#define HH 8
#define HD 32

#define FPSCALE 524288.0f            // 2^19 fixed-point scale for S
#define RFPSCALE (1.0f / 524288.0f)
#define QSCALE 0.25503486f           // (1/sqrt(32)) * log2(e)  -> use exp2

typedef __bf16 bf8_t __attribute__((ext_vector_type(8)));
typedef __bf16 bf4_t __attribute__((ext_vector_type(4)));
typedef float f4_t __attribute__((ext_vector_type(4)));

// raw 2^x (scores are small & well-conditioned; no denormal/edge fixup needed)
static __device__ __forceinline__ float fexp2(float x) {
#if __has_builtin(__builtin_amdgcn_exp2f)
    return __builtin_amdgcn_exp2f(x);
#else
    float r;
    asm("v_exp_f32 %0, %1" : "=v"(r) : "v"(x));
    return r;
#endif
}

// ---------------- kernel A: QK-GEMM + wv sigmoid + zero Si ----------
// blocks 0..511   : Q/K = (x+pe) @ W (+bias); 64 rows x 64 cols per block
// blocks 512..639 : w[hb][k] = sigmoid(x[b,L-1-k] . Wv[:,h]) * FPSCALE
// blocks 640..671 : zero Si (int4)
__global__ __launch_bounds__(256) void k_A(const float* __restrict__ x,
                                           const float* __restrict__ pe,
                                           const float* __restrict__ Wq,
                                           const float* __restrict__ Wk,
                                           const float* __restrict__ Wv,
                                           const float* __restrict__ bq,
                                           const float* __restrict__ bk,
                                           float* __restrict__ w,
                                           __bf16* __restrict__ Qb,
                                           __bf16* __restrict__ Kb,
                                           int* __restrict__ Si) {
    __shared__ __align__(16) char smem[34816];
    int gb = blockIdx.x;
    int tid = threadIdx.x;

    if (gb < 512) {
        // ---- QK GEMM role: 64 rows x 64 cols ----
        __bf16* xs = (__bf16*)smem;                   // 64 x 136
        __bf16* Wt = (__bf16*)(smem + 64 * 136 * 2);  // 64 x 136 (c-major, transposed)
        int jr = gb >> 3, y = gb & 7;
        int row0 = jr * 64;
        bool isK = y >= 4;
        int cbase = (y & 3) * 64;
        const float* W = isK ? Wk : Wq;

        // stage x+pe -> bf16 LDS (64 rows x 128 cols), float4 loads
        #pragma unroll
        for (int i = 0; i < 8; i++) {
            int idx4 = tid + i * 256;                 // 0..2047 float4s
            int row = idx4 >> 5, col4 = idx4 & 31;
            float4 xv = ((const float4*)x)[row0 * 32 + idx4];
            float4 pv = ((const float4*)pe)[((row0 + row) & (LSEQ - 1)) * 32 + col4];
            bf4_t o = {(__bf16)(xv.x + pv.x), (__bf16)(xv.y + pv.y),
                       (__bf16)(xv.z + pv.z), (__bf16)(xv.w + pv.w)};
            *(bf4_t*)&xs[row * 136 + col4 * 4] = o;
        }
        // stage W stripe transposed: Wt[c][d] = W[d][cbase+c]
        #pragma unroll
        for (int i = 0; i < 8; i++) {
            int idx4 = tid + i * 256;                 // 0..2047
            int d = idx4 >> 4, c4 = (idx4 & 15) * 4;
            float4 wv4 = *(const float4*)(W + d * 256 + cbase + c4);
            Wt[(c4 + 0) * 136 + d] = (__bf16)wv4.x;
            Wt[(c4 + 1) * 136 + d] = (__bf16)wv4.y;
            Wt[(c4 + 2) * 136 + d] = (__bf16)wv4.z;
            Wt[(c4 + 3) * 136 + d] = (__bf16)wv4.w;
        }
        __syncthreads();

        int wid = tid >> 6, lane = tid & 63;
        int lm = lane & 15, lq = lane >> 4;
        int c0loc = wid * 16;
        f4_t acc0 = {0,0,0,0}, acc1 = {0,0,0,0}, acc2 = {0,0,0,0}, acc3 = {0,0,0,0};
        #pragma unroll
        for (int s = 0; s < 4; s++) {
            bf8_t bw = *(const bf8_t*)&Wt[(c0loc + lm) * 136 + lq * 8 + s * 32];
            bf8_t a0 = *(const bf8_t*)&xs[(0  + lm) * 136 + lq * 8 + s * 32];
            bf8_t a1 = *(const bf8_t*)&xs[(16 + lm) * 136 + lq * 8 + s * 32];
            bf8_t a2 = *(const bf8_t*)&xs[(32 + lm) * 136 + lq * 8 + s * 32];
            bf8_t a3 = *(const bf8_t*)&xs[(48 + lm) * 136 + lq * 8 + s * 32];
            acc0 = __builtin_amdgcn_mfma_f32_16x16x32_bf16(a0, bw, acc0, 0, 0, 0);
            acc1 = __builtin_amdgcn_mfma_f32_16x16x32_bf16(a1, bw, acc1, 0, 0, 0);
            acc2 = __builtin_amdgcn_mfma_f32_16x16x32_bf16(a2, bw, acc2, 0, 0, 0);
            acc3 = __builtin_amdgcn_mfma_f32_16x16x32_bf16(a3, bw, acc3, 0, 0, 0);
        }
        int c = cbase + c0loc + lm;                   // 0..255
        float bv = (isK ? bk : bq)[c];
        float qs = isK ? 1.f : QSCALE;
        __bf16* Out = isK ? Kb : Qb;
        int h = c >> 5, hd = c & 31;
        f4_t accs[4] = {acc0, acc1, acc2, acc3};
        #pragma unroll
        for (int rs = 0; rs < 4; rs++) {
            #pragma unroll
            for (int r = 0; r < 4; r++) {
                int row = row0 + rs * 16 + lq * 4 + r;   // = b*2048 + l
                int b_ = row >> 11, l = row & (LSEQ - 1);
                Out[((h * BB + b_) * LSEQ + l) * HD + hd] =
                    (__bf16)((accs[rs][r] + bv) * qs);
            }
        }
    } else if (gb < 640) {
        // ---- wv sigmoid role (FPSCALE folded in) ----
        float* xsf = (float*)smem;                    // 32*132
        float* wvf = (float*)(smem + 32 * 132 * 4);   // 1024
        int r0 = (gb - 512) * 32;
        for (int i = 0; i < 16; i++) {
            int idx = tid + i * 256;
            xsf[(idx >> 7) * 132 + (idx & 127)] = x[r0 * 128 + idx];
        }
        for (int i = 0; i < 4; i++) {
            int idx = tid + i * 256;
            wvf[idx] = Wv[idx];
        }
        __syncthreads();
        int rl = tid >> 3, h = tid & 7;
        float acc = 0.f;
        #pragma unroll 8
        for (int d = 0; d < 128; d++) acc += xsf[rl * 132 + d] * wvf[d * 8 + h];
        float sg = 1.f / (1.f + __expf(-acc));
        int r = r0 + rl;
        int b = r >> 11, l = r & (LSEQ - 1);
        w[(h * BB + b) * LSEQ + (LSEQ - 1 - l)] = sg * FPSCALE;
    } else {
        int4 z = {0, 0, 0, 0};
        ((int4*)Si)[(gb - 640) * 256 + tid] = z;
    }
}

// ---------------- kernel F: fused den + triangle scatter, 8-wave blocks -----
// grid (64 q-stripes, 16 hb), 512 threads = 8 waves, each block owns 32 q rows.
// Waves: g = wid>>2 selects the 16-q-row group (2 groups), h = wid&3 the
// k-quarter (4 sweeps per group).
// phase 1: den: wave sweeps its k-quarter (32 subtiles), shfl reduce over lm,
//          then 4-way combine via LDS. rdv stays in registers.
// phase 2: group triangle; boundary subtile by h==0; full subtiles t = h,
//          t += 4. Scatter into shared 2048-bin Sloc (the ~1M
//          SQ_LDS_BANK_CONFLICT is inherent free 2-way wave64 aliasing).
// phase 3: device-scope atomic accumulate into S (one pass per 32 q rows).
__global__ __launch_bounds__(512) void k_F(const __bf16* __restrict__ Qb,
                                           const __bf16* __restrict__ Kb,
                                           const float* __restrict__ w,
                                           int* __restrict__ S) {
    __shared__ int Sloc[2048];
    __shared__ float dred[128];

    int hb = blockIdx.y;
    int q0 = blockIdx.x << 5;                    // 32 q rows per block
    int tid = threadIdx.x;
    int wid = tid >> 6, lane = tid & 63;
    int lm = lane & 15, lq = lane >> 4;
    int g = wid >> 2, h = wid & 3;               // 2 groups x 4 k-quarters
    int qg0 = q0 + g * 16;                       // this wave's 16-q-row group

    int4 z4 = {0, 0, 0, 0};
    ((int4*)Sloc)[tid] = z4;                     // 512*16B = 8KB

    const __bf16* Qhb = Qb + hb * LSEQ * HD;
    const __bf16* Khb = Kb + hb * LSEQ * HD;
    bf8_t aq = *(const bf8_t*)(Qhb + (qg0 + lm) * HD + lq * 8);

    // ---- phase 1: denominators, k split 4-way among the group's waves ----
    float dsum[4] = {0.f, 0.f, 0.f, 0.f};
    #pragma unroll 4
    for (int s = h; s < 128; s += 4) {
        bf8_t bk_ = *(const bf8_t*)(Khb + (s * 16 + lm) * HD + lq * 8);
        f4_t z = {0.f, 0.f, 0.f, 0.f};
        f4_t sc = __builtin_amdgcn_mfma_f32_16x16x32_bf16(aq, bk_, z, 0, 0, 0);
        #pragma unroll
        for (int r = 0; r < 4; r++) dsum[r] += fexp2(sc[r]);
    }
    #pragma unroll
    for (int r = 0; r < 4; r++) {
        float v = dsum[r];
        v += __shfl_xor(v, 1);
        v += __shfl_xor(v, 2);
        v += __shfl_xor(v, 4);
        v += __shfl_xor(v, 8);
        dsum[r] = v;
    }
    if (lm == 0) {
        #pragma unroll
        for (int r = 0; r < 4; r++) dred[wid * 16 + lq * 4 + r] = dsum[r];
    }
    __syncthreads();
    float rdv[4];
    #pragma unroll
    for (int r = 0; r < 4; r++) {
        int base = g * 64 + lq * 4 + r;          // group g waves: dred[g*64 .. +63]
        float d = dred[base] + dred[base + 16] + dred[base + 32] + dred[base + 48];
        rdv[r] = 1.0f / d;
    }

    // ---- phase 2: upper-triangle scatter for this wave's group ----
    const float* whb = w + hb * LSEQ;
    int qrow = qg0 + lq * 4;

    if (h == 0) {
        // boundary subtile (k0s = qg0): per-element m>=0 mask
        bf8_t bk_ = *(const bf8_t*)(Khb + (qg0 + lm) * HD + lq * 8);
        f4_t z = {0.f, 0.f, 0.f, 0.f};
        f4_t sc = __builtin_amdgcn_mfma_f32_16x16x32_bf16(aq, bk_, z, 0, 0, 0);
        float wv = whb[qg0 + lm];
        #pragma unroll
        for (int r = 0; r < 4; r++) {
            int m = lm - lq * 4 - r;
            if (m >= 0) {
                int iv = __float2int_rn(fexp2(sc[r]) * rdv[r] * wv);
                atomicAdd(&Sloc[m], iv);
            }
        }
    }
    // full subtiles: k0s = qg0 + 16 + 16t, t split 4-way among the group
    int nfull = 127 - (qg0 >> 4);
    #pragma unroll 2
    for (int t = h; t < nfull; t += 4) {
        int k0s = qg0 + 16 + t * 16;
        bf8_t bk_ = *(const bf8_t*)(Khb + (k0s + lm) * HD + lq * 8);
        f4_t z = {0.f, 0.f, 0.f, 0.f};
        f4_t sc = __builtin_amdgcn_mfma_f32_16x16x32_bf16(aq, bk_, z, 0, 0, 0);
        float wv = whb[k0s + lm];
        int base = k0s + lm - qrow;              // m for r=0; strictly > 0 here
        #pragma unroll
        for (int r = 0; r < 4; r++) {
            int iv = __float2int_rn(fexp2(sc[r]) * rdv[r] * wv);
            atomicAdd(&Sloc[base - r], iv);      // native ds_add
        }
    }
    __syncthreads();

    // ---- phase 3: global atomic accumulate (device-scope, no fence) ----
    int M = LSEQ - q0;
    int* Sg = S + hb * LSEQ;
    for (int i = tid; i < M; i += 512) {
        int v = Sloc[i];
        if (v) atomicAdd(&Sg[i], v);
    }
}

// ---------------- kernel 3: pooling epilogue (int -> float) ----------------
__global__ __launch_bounds__(256) void k_out(const int* __restrict__ S,
                                             float* __restrict__ out) {
    int idx = blockIdx.x * 256 + threadIdx.x;       // (b*2048 + m)*8 + h
    int h = idx & 7;
    int m = (idx >> 3) & (LSEQ - 1);
    int b = idx >> 14;
    const int* Sr = S + (h * BB + b) * LSEQ;
    float s = (float)Sr[m];
    float cnt = 3.f;
    if (m > 0) s += (float)Sr[m - 1]; else cnt = 2.f;
    if (m < LSEQ - 1) s += (float)Sr[m + 1]; else cnt = 2.f;
    out[idx] = s * RFPSCALE / cnt;
}

extern "C" void kernel_launch(void* const* d_in, const int* in_sizes, int n_in,
                              void* d_out, int out_size, void* d_ws, size_t ws_size,
                              hipStream_t stream) {
    const float* x  = (const float*)d_in[0];
    const float* pe = (const float*)d_in[1];
    const float* Wq = (const float*)d_in[2];
    const float* bq = (const float*)d_in[3];
    const float* Wk = (const float*)d_in[4];
    const float* bk = (const float*)d_in[5];
    const float* Wv = (const float*)d_in[6];
    float* out = (float*)d_out;

    char* ws = (char*)d_ws;
    int*    Si  = (int*)(ws);                              // 128 KB
    float*  w   = (float*)(ws + 131072);                   // 128 KB
    __bf16* Qb  = (__bf16*)(ws + 262144);                  // 2 MB
    __bf16* Kb  = (__bf16*)(ws + 262144 + 2097152);        // 2 MB

    k_A<<<672, 256, 0, stream>>>(x, pe, Wq, Wk, Wv, bq, bk, w, Qb, Kb, Si);
    k_F<<<dim3(64, 16), 512, 0, stream>>>(Qb, Kb, w, Si);
    k_out<<<128, 256, 0, stream>>>(Si, out);
}